// Round 11
// baseline (143.476 us; speedup 1.0000x reference)
//
#include <hip/hip_runtime.h>

#define N 8192
#define D 256
#define INV_TAU 14.285714285714286f
#define LOG2E 1.4426950408889634f
#define EPSN 1e-6f

// fused-lse kernel geometry
#define RT 128            // rows per block (4 waves x 32 rows)
#define CT 32             // cols per LDS tile
#define CSPLIT 8          // column splits across blocks
#define CPB (N / CSPLIT)  // 1024 cols per block
#define NTILES (CPB / CT) // 32 tiles
#define TILEB (CT * 512)  // 16 KB per tile buffer
#define MAXC 96           // max rows per label class (avg 8, max ~25 for this data)

typedef unsigned int u32x4 __attribute__((ext_vector_type(4)));
typedef __bf16 bf16x8 __attribute__((ext_vector_type(8)));
typedef float f32x4 __attribute__((ext_vector_type(4)));

__device__ inline unsigned short f2bf(float x) {
    unsigned int u = __builtin_bit_cast(unsigned int, x);
    u += 0x7fffu + ((u >> 16) & 1u);   // round-to-nearest-even (finite inputs)
    return (unsigned short)(u >> 16);
}

__device__ inline float bf2f(unsigned short u) {
    return __builtin_bit_cast(float, (unsigned int)u << 16);
}

// One wave per row: normalize rows -> bf16. A is prescaled by INV_TAU*LOG2E so
// the MFMA output is directly the base-2 logit (exp2 = single v_exp_f32).
// Also zeroes diag-side accumulators and the class-count array.
__global__ void ntx_prep(const float* __restrict__ im, const float* __restrict__ rec,
                         unsigned short* __restrict__ A, unsigned short* __restrict__ Bm,
                         float* __restrict__ diag, float* __restrict__ rowsum,
                         int* __restrict__ cnt, float* __restrict__ out) {
    const int wave = threadIdx.x >> 6;
    const int lane = threadIdx.x & 63;
    const int row  = blockIdx.x * 4 + wave;

    const float4 a = ((const float4*)(im  + (size_t)row * D))[lane];
    const float4 b = ((const float4*)(rec + (size_t)row * D))[lane];

    float ssa = a.x*a.x + a.y*a.y + a.z*a.z + a.w*a.w;
    float ssb = b.x*b.x + b.y*b.y + b.z*b.z + b.w*b.w;
    float dt  = a.x*b.x + a.y*b.y + a.z*b.z + a.w*b.w;
    #pragma unroll
    for (int o = 32; o; o >>= 1) {
        ssa += __shfl_xor(ssa, o);
        ssb += __shfl_xor(ssb, o);
        dt  += __shfl_xor(dt , o);
    }
    const float ra = 1.0f / fmaxf(sqrtf(ssa), EPSN);
    const float rb = 1.0f / fmaxf(sqrtf(ssb), EPSN);
    const float sa = ra * (INV_TAU * LOG2E);   // scale-invariant bf16 error

    ushort4 pa, pb;
    pa.x = f2bf(a.x*sa); pa.y = f2bf(a.y*sa); pa.z = f2bf(a.z*sa); pa.w = f2bf(a.w*sa);
    pb.x = f2bf(b.x*rb); pb.y = f2bf(b.y*rb); pb.z = f2bf(b.z*rb); pb.w = f2bf(b.w*rb);
    *(ushort4*)(A  + (size_t)row * D + lane * 4) = pa;
    *(ushort4*)(Bm + (size_t)row * D + lane * 4) = pb;

    if (lane == 0) {
        diag[row]   = dt * ra * rb * INV_TAU;  // fp32 i2r[i,i] (natural-log units)
        rowsum[row] = 0.0f;                    // ws is poisoned each launch
    }
    if (blockIdx.x < 4) cnt[blockIdx.x * 256 + threadIdx.x] = 0;
    if (blockIdx.x == 0 && threadIdx.x == 0) out[0] = 0.0f;
}

// Bucket rows by label class. grid = N/256.
__global__ void ntx_bucket(const int* __restrict__ labels, int* __restrict__ cnt,
                           int* __restrict__ bucket) {
    const int i = blockIdx.x * 256 + threadIdx.x;
    const int c = labels[i];
    const int pos = atomicAdd(&cnt[c], 1);
    if (pos < MAXC) bucket[c * MAXC + pos] = i;
}

// Stage a full 32-col x 512-B tile, cooperative across 4 waves (wave w owns
// chunks csk = w*4 .. w*4+3; chunk csk holds fragment (cs=csk>>3, k=csk&7)).
// LDS FRAGMENT ORDER: chunk csk at byte csk*1024 + lane*16 (HW linear dest ->
// zero write conflicts; reads are wave-linear 1 KB -> zero read conflicts).
__device__ __forceinline__ void stage_tile4(const unsigned short* __restrict__ Bm,
                                            int colt, int wave, int lane,
                                            unsigned char* lb) {
    const int g = lane >> 4, n16 = lane & 15;
    #pragma unroll
    for (int p = 0; p < 4; ++p) {
        const int csk = wave * 4 + p;
        const int cs = csk >> 3, k = csk & 7;
        const unsigned short* gs =
            Bm + (size_t)(colt + cs * 16 + n16) * D + k * 32 + g * 8;
        __builtin_amdgcn_global_load_lds(
            (const __attribute__((address_space(1))) unsigned int*)gs,
            (__attribute__((address_space(3))) unsigned int*)(lb + csk * 1024),
            16, 0, 0);
    }
}

// read one cs-half chunk (8 x ds_read_b128, wave-linear, conflict-free)
__device__ __forceinline__ void read_chunk(const unsigned char* buf, int cs, int lane,
                                           bf16x8 (&bf)[8]) {
    #pragma unroll
    for (int k = 0; k < 8; ++k)
        bf[k] = __builtin_bit_cast(
            bf16x8, *(const u32x4*)(buf + (cs * 8 + k) * 1024 + lane * 16));
}

__device__ __forceinline__ void mfma_chunk(const bf16x8 (&afrag)[2][8],
                                           const bf16x8 (&bf)[8], f32x4 (&cp)[2]) {
    cp[0] = (f32x4){0.f, 0.f, 0.f, 0.f};
    cp[1] = (f32x4){0.f, 0.f, 0.f, 0.f};
    __builtin_amdgcn_s_setprio(1);
    #pragma unroll
    for (int k = 0; k < 8; ++k)
        #pragma unroll
        for (int rs = 0; rs < 2; ++rs)
            cp[rs] = __builtin_amdgcn_mfma_f32_16x16x32_bf16(
                         afrag[rs][k], bf[k], cp[rs], 0, 0, 0);
    __builtin_amdgcn_s_setprio(0);
}

__device__ __forceinline__ void expacc(const f32x4 (&cp)[2], float (&acc)[2][4]) {
    #pragma unroll
    for (int rs = 0; rs < 2; ++rs)
        #pragma unroll
        for (int q = 0; q < 4; ++q)
            acc[rs][q] += __builtin_amdgcn_exp2f(cp[rs][q]);
}

// Fused GEMM + UNMASKED sum-of-exp per row (mask handled by ntx_pairsfin).
// Intra-wave cross-tile pipeline: depth-3 staging over 4 LDS buffers; each
// chunk issues the NEXT chunk's ds_reads, then runs MFMA on the CURRENT
// chunk's registers (no read->MFMA dependency inside a chunk), then exp-acc
// of the previous chunk's results. LDS, matrix, and trans pipes are fed
// concurrently from each wave. Per-tile wait is vmcnt(4); full drain only in
// the last 4 tiles. 512 blocks (2/CU), 4 waves x 32 rows.
__global__ __launch_bounds__(256, 2)
void ntx_lse(const unsigned short* __restrict__ A, const unsigned short* __restrict__ Bm,
             float* __restrict__ rowsum) {
    __shared__ __align__(128) unsigned char Bs[4][TILEB];  // 64 KB

    const int wave = threadIdx.x >> 6;
    const int lane = threadIdx.x & 63;
    const int g    = lane >> 4;    // 0..3 (k-quad)
    const int n16  = lane & 15;    // 0..15

    const int rowblk = blockIdx.x & (N / RT - 1);   // 0..63
    const int colblk = blockIdx.x >> 6;             // 0..7
    const int row0 = rowblk * RT + wave * 32;       // this wave's 32 rows
    const int col0 = colblk * CPB;

    // A fragments for 32 rows x K=256 in registers (64 VGPRs).
    // A-operand layout: m = lane&15, k = (lane>>4)*8 + j
    bf16x8 afrag[2][8];
    #pragma unroll
    for (int rs = 0; rs < 2; ++rs) {
        const int r = row0 + rs * 16 + n16;
        #pragma unroll
        for (int k = 0; k < 8; ++k)
            afrag[rs][k] = __builtin_bit_cast(
                bf16x8, *(const u32x4*)(A + (size_t)r * D + k * 32 + g * 8));
    }

    float acc[2][4] = {{0.f,0.f,0.f,0.f},{0.f,0.f,0.f,0.f}};

    // previous-chunk MFMA results; -inf -> exp2 = 0 on the first chunk
    f32x4 cp[2];
    cp[0] = (f32x4){-__builtin_huge_valf(), -__builtin_huge_valf(),
                    -__builtin_huge_valf(), -__builtin_huge_valf()};
    cp[1] = cp[0];

    // prologue: tiles 0,1,2 staged (12 loads); vmcnt(4) -> 0,1 complete
    stage_tile4(Bm, col0 + 0 * CT, wave, lane, &Bs[0][0]);
    stage_tile4(Bm, col0 + 1 * CT, wave, lane, &Bs[1][0]);
    stage_tile4(Bm, col0 + 2 * CT, wave, lane, &Bs[2][0]);
    asm volatile("s_waitcnt vmcnt(4)" ::: "memory");
    __builtin_amdgcn_s_barrier();
    __builtin_amdgcn_sched_barrier(0);

    bf16x8 bfA[8], bfB[8];
    read_chunk(&Bs[0][0], 0, lane, bfA);      // chunk(0,0)

    for (int t = 0; t < NTILES; ++t) {
        // pin A fragments (opaque loop-carried values -> no remat)
        #pragma unroll
        for (int rs = 0; rs < 2; ++rs)
            #pragma unroll
            for (int k = 0; k < 8; ++k)
                asm volatile("" : "+v"(afrag[rs][k]));

        if (t + 3 < NTILES)
            stage_tile4(Bm, col0 + (t + 3) * CT, wave, lane, &Bs[(t + 3) & 3][0]);

        // h=0: lookahead chunk(t,1); exp prev; MFMA chunk(t,0) from bfA
        read_chunk(&Bs[t & 3][0], 1, lane, bfB);
        expacc(cp, acc);
        mfma_chunk(afrag, bfA, cp);

        // h=1: lookahead chunk(t+1,0) (staged-complete by invariant);
        //      exp prev; MFMA chunk(t,1) from bfB
        if (t + 1 < NTILES)
            read_chunk(&Bs[(t + 1) & 3][0], 0, lane, bfA);
        expacc(cp, acc);
        mfma_chunk(afrag, bfB, cp);

        // counted wait: completes tile t+2; t+3 stays in flight. Tail: drain.
        if (t < NTILES - 4)
            asm volatile("s_waitcnt vmcnt(4)" ::: "memory");
        else
            asm volatile("s_waitcnt vmcnt(0)" ::: "memory");
        __builtin_amdgcn_s_barrier();
        __builtin_amdgcn_sched_barrier(0);
    }
    expacc(cp, acc);   // final chunk's results

    // reduce partial row sums across the 16 lanes sharing each row group
    #pragma unroll
    for (int rs = 0; rs < 2; ++rs)
        #pragma unroll
        for (int q = 0; q < 4; ++q) {
            float v = acc[rs][q];
            v += __shfl_xor(v, 1);
            v += __shfl_xor(v, 2);
            v += __shfl_xor(v, 4);
            v += __shfl_xor(v, 8);
            if (n16 == 0)
                atomicAdd(&rowsum[row0 + rs * 16 + g * 4 + q], v);
        }
}

// Fused sparse mask correction + finish, one WAVE per row (runs AFTER lse):
// subtract the row's same-label off-diagonal exps (avg 8, 1-deep prefetch),
// then contribute log(rowsum - corr) - diag to the mean.
__global__ void ntx_pairsfin(const unsigned short* __restrict__ A,
                             const unsigned short* __restrict__ Bm,
                             const int* __restrict__ labels,
                             const int* __restrict__ cnt, const int* __restrict__ bucket,
                             const float* __restrict__ diag,
                             const float* __restrict__ rowsum,
                             float* __restrict__ out) {
    __shared__ float red[4];
    const int wave = threadIdx.x >> 6;
    const int lane = threadIdx.x & 63;
    const int i = blockIdx.x * 4 + wave;        // this wave's row
    const int c = labels[i];
    const int m = min(cnt[c], MAXC);

    float corr = 0.f;
    if (m >= 2) {
        const ushort4 av = *(const ushort4*)(A + (size_t)i * D + lane * 4);
        const float a0 = bf2f(av.x), a1 = bf2f(av.y), a2 = bf2f(av.z), a3 = bf2f(av.w);

        int jr_n = bucket[c * MAXC];
        ushort4 bv_n = *(const ushort4*)(Bm + (size_t)jr_n * D + lane * 4);

        for (int j = 0; j < m; ++j) {
            const int jr = jr_n;
            const ushort4 bv = bv_n;
            if (j + 1 < m) {                    // prefetch next pair
                jr_n = bucket[c * MAXC + j + 1];
                bv_n = *(const ushort4*)(Bm + (size_t)jr_n * D + lane * 4);
            }
            if (jr == i) continue;              // keep the diagonal
            float d = a0*bf2f(bv.x) + a1*bf2f(bv.y) + a2*bf2f(bv.z) + a3*bf2f(bv.w);
            #pragma unroll
            for (int o = 32; o; o >>= 1) d += __shfl_xor(d, o);
            corr += __builtin_amdgcn_exp2f(d);  // d is the base-2 logit
        }
    }
    if (lane == 0) red[wave] = logf(rowsum[i] - corr) - diag[i];
    __syncthreads();
    if (threadIdx.x == 0)
        atomicAdd(out, (red[0] + red[1] + red[2] + red[3]) * (1.0f / (float)N));
}

extern "C" void kernel_launch(void* const* d_in, const int* in_sizes, int n_in,
                              void* d_out, int out_size, void* d_ws, size_t ws_size,
                              hipStream_t stream) {
    const float* im     = (const float*)d_in[0];
    const float* rec    = (const float*)d_in[1];
    const int*   labels = (const int*)d_in[2];
    float* out = (float*)d_out;

    unsigned short* A  = (unsigned short*)d_ws;           // 4 MB bf16 im_n * INV_TAU*LOG2E
    unsigned short* Bm = A + (size_t)N * D;               // 4 MB bf16 rec_n
    float* diag   = (float*)(Bm + (size_t)N * D);         // 32 KB
    float* rowsum = diag + N;                             // 32 KB
    int*   cnt    = (int*)(rowsum + N);                   // 4 KB
    int*   bucket = cnt + 1024;                           // 384 KB

    ntx_prep<<<N / 4, 256, 0, stream>>>(im, rec, A, Bm, diag, rowsum, cnt, out);
    ntx_bucket<<<N / 256, 256, 0, stream>>>(labels, cnt, bucket);
    ntx_lse<<<(N / RT) * CSPLIT, 256, 0, stream>>>(A, Bm, rowsum);
    ntx_pairsfin<<<N / 4, 256, 0, stream>>>(A, Bm, labels, cnt, bucket, diag, rowsum, out);
}

// Round 12
// 120.367 us; speedup vs baseline: 1.1920x; 1.1920x over previous
//
#include <hip/hip_runtime.h>

#define N 8192
#define D 256
#define INV_TAU 14.285714285714286f
#define LOG2E 1.4426950408889634f
#define EPSN 1e-6f

// fused-lse kernel geometry
#define RT 256            // rows per block (4 waves x 64 rows)
#define CT 32             // cols per LDS tile
#define CSPLIT 16         // column splits across blocks
#define CPB (N / CSPLIT)  // 512 cols per block
#define NTILES (CPB / CT) // 16 tiles
#define MAXC 96           // max rows per label class (avg 8, max ~25 for this data)

typedef unsigned int u32x4 __attribute__((ext_vector_type(4)));
typedef __bf16 bf16x8 __attribute__((ext_vector_type(8)));
typedef float f32x4 __attribute__((ext_vector_type(4)));

__device__ inline unsigned short f2bf(float x) {
    unsigned int u = __builtin_bit_cast(unsigned int, x);
    u += 0x7fffu + ((u >> 16) & 1u);   // round-to-nearest-even (finite inputs)
    return (unsigned short)(u >> 16);
}

__device__ inline float bf2f(unsigned short u) {
    return __builtin_bit_cast(float, (unsigned int)u << 16);
}

// One wave per row: normalize rows -> bf16. A is prescaled by INV_TAU*LOG2E so
// the MFMA output is directly the base-2 logit (exp2 = single v_exp_f32).
// Also zeroes diag-side accumulators and the class-count array.
__global__ void ntx_prep(const float* __restrict__ im, const float* __restrict__ rec,
                         unsigned short* __restrict__ A, unsigned short* __restrict__ Bm,
                         float* __restrict__ diag, float* __restrict__ rowsum,
                         int* __restrict__ cnt, float* __restrict__ out) {
    const int wave = threadIdx.x >> 6;
    const int lane = threadIdx.x & 63;
    const int row  = blockIdx.x * 4 + wave;

    const float4 a = ((const float4*)(im  + (size_t)row * D))[lane];
    const float4 b = ((const float4*)(rec + (size_t)row * D))[lane];

    float ssa = a.x*a.x + a.y*a.y + a.z*a.z + a.w*a.w;
    float ssb = b.x*b.x + b.y*b.y + b.z*b.z + b.w*b.w;
    float dt  = a.x*b.x + a.y*b.y + a.z*b.z + a.w*b.w;
    #pragma unroll
    for (int o = 32; o; o >>= 1) {
        ssa += __shfl_xor(ssa, o);
        ssb += __shfl_xor(ssb, o);
        dt  += __shfl_xor(dt , o);
    }
    const float ra = 1.0f / fmaxf(sqrtf(ssa), EPSN);
    const float rb = 1.0f / fmaxf(sqrtf(ssb), EPSN);
    const float sa = ra * (INV_TAU * LOG2E);   // scale-invariant bf16 error

    ushort4 pa, pb;
    pa.x = f2bf(a.x*sa); pa.y = f2bf(a.y*sa); pa.z = f2bf(a.z*sa); pa.w = f2bf(a.w*sa);
    pb.x = f2bf(b.x*rb); pb.y = f2bf(b.y*rb); pb.z = f2bf(b.z*rb); pb.w = f2bf(b.w*rb);
    *(ushort4*)(A  + (size_t)row * D + lane * 4) = pa;
    *(ushort4*)(Bm + (size_t)row * D + lane * 4) = pb;

    if (lane == 0) {
        diag[row]   = dt * ra * rb * INV_TAU;  // fp32 i2r[i,i] (natural-log units)
        rowsum[row] = 0.0f;                    // ws is poisoned each launch
    }
    if (blockIdx.x < 4) cnt[blockIdx.x * 256 + threadIdx.x] = 0;
    if (blockIdx.x == 0 && threadIdx.x == 0) out[0] = 0.0f;
}

// Bucket rows by label class. grid = N/256.
__global__ void ntx_bucket(const int* __restrict__ labels, int* __restrict__ cnt,
                           int* __restrict__ bucket) {
    const int i = blockIdx.x * 256 + threadIdx.x;
    const int c = labels[i];
    const int pos = atomicAdd(&cnt[c], 1);
    if (pos < MAXC) bucket[c * MAXC + pos] = i;
}

// Sparse mask correction, one WAVE per row: loop over the row's class members
// (avg 8, max ~24) with 1-deep prefetch so pair j+1's loads hide under pair
// j's dot/reduce/exp. grid = N/4 blocks; low VGPR -> full occupancy.
__global__ void ntx_pairs(const unsigned short* __restrict__ A,
                          const unsigned short* __restrict__ Bm,
                          const int* __restrict__ labels,
                          const int* __restrict__ cnt, const int* __restrict__ bucket,
                          float* __restrict__ rowsum) {
    const int wave = threadIdx.x >> 6;
    const int lane = threadIdx.x & 63;
    const int i = blockIdx.x * 4 + wave;        // this wave's row
    const int c = labels[i];
    const int m = min(cnt[c], MAXC);
    if (m < 2) return;

    const ushort4 av = *(const ushort4*)(A + (size_t)i * D + lane * 4);
    const float a0 = bf2f(av.x), a1 = bf2f(av.y), a2 = bf2f(av.z), a3 = bf2f(av.w);

    int jr_n = bucket[c * MAXC];
    ushort4 bv_n = *(const ushort4*)(Bm + (size_t)jr_n * D + lane * 4);

    float corr = 0.f;
    for (int j = 0; j < m; ++j) {
        const int jr = jr_n;
        const ushort4 bv = bv_n;
        if (j + 1 < m) {                        // prefetch next pair
            jr_n = bucket[c * MAXC + j + 1];
            bv_n = *(const ushort4*)(Bm + (size_t)jr_n * D + lane * 4);
        }
        if (jr == i) continue;                  // keep the diagonal
        float d = a0*bf2f(bv.x) + a1*bf2f(bv.y) + a2*bf2f(bv.z) + a3*bf2f(bv.w);
        #pragma unroll
        for (int o = 32; o; o >>= 1) d += __shfl_xor(d, o);
        corr += __builtin_amdgcn_exp2f(d);      // d is the base-2 logit
    }
    if (lane == 0) atomicAdd(&rowsum[i], -corr);
}

// Stage a full 32-col x 512-B tile, cooperative across 4 waves (wave w owns
// chunks csk = w*4 .. w*4+3; chunk csk holds fragment (cs=csk>>3, k=csk&7)).
// LDS FRAGMENT ORDER: chunk csk at byte csk*1024 + lane*16 (HW linear dest ->
// zero write conflicts; reads are wave-linear 1 KB -> zero read conflicts).
__device__ __forceinline__ void stage_tile4(const unsigned short* __restrict__ Bm,
                                            int colt, int wave, int lane,
                                            unsigned char* lb) {
    const int g = lane >> 4, n16 = lane & 15;
    #pragma unroll
    for (int p = 0; p < 4; ++p) {
        const int csk = wave * 4 + p;
        const int cs = csk >> 3, k = csk & 7;
        const unsigned short* gs =
            Bm + (size_t)(colt + cs * 16 + n16) * D + k * 32 + g * 8;
        __builtin_amdgcn_global_load_lds(
            (const __attribute__((address_space(1))) unsigned int*)gs,
            (__attribute__((address_space(3))) unsigned int*)(lb + csk * 1024),
            16, 0, 0);
    }
}

// One tile's compute (2 cs-phases); optionally interleaves the issue of tile
// t+2's staging loads (2 per cs-phase) into buffer stg != cur.
template<bool STAGE>
__device__ __forceinline__ void tile_step(const unsigned short* __restrict__ Bm,
                                          int colstage, int wave, int lane,
                                          const unsigned char* cur, unsigned char* stg,
                                          const bf16x8 (&afrag)[4][8], float (&acc)[4][4]) {
    const int g = lane >> 4, n16 = lane & 15;
    #pragma unroll
    for (int cs = 0; cs < 2; ++cs) {
        if constexpr (STAGE) {
            #pragma unroll
            for (int p = cs * 2; p < cs * 2 + 2; ++p) {
                const int csk = wave * 4 + p;
                const int scs = csk >> 3, sk = csk & 7;
                const unsigned short* gs =
                    Bm + (size_t)(colstage + scs * 16 + n16) * D + sk * 32 + g * 8;
                __builtin_amdgcn_global_load_lds(
                    (const __attribute__((address_space(1))) unsigned int*)gs,
                    (__attribute__((address_space(3))) unsigned int*)(stg + csk * 1024),
                    16, 0, 0);
            }
        }
        bf16x8 bfrag[8];
        #pragma unroll
        for (int k = 0; k < 8; ++k)
            bfrag[k] = __builtin_bit_cast(
                bf16x8, *(const u32x4*)(cur + (cs * 8 + k) * 1024 + lane * 16));

        f32x4 c[4];
        __builtin_amdgcn_s_setprio(1);
        #pragma unroll
        for (int rs = 0; rs < 4; ++rs) {
            c[rs] = (f32x4){0.f, 0.f, 0.f, 0.f};
            #pragma unroll
            for (int k = 0; k < 8; ++k)
                c[rs] = __builtin_amdgcn_mfma_f32_16x16x32_bf16(
                            afrag[rs][k], bfrag[k], c[rs], 0, 0, 0);
        }
        __builtin_amdgcn_s_setprio(0);
        #pragma unroll
        for (int rs = 0; rs < 4; ++rs)
            #pragma unroll
            for (int q = 0; q < 4; ++q)
                acc[rs][q] += __builtin_amdgcn_exp2f(c[rs][q]);
    }
}

// Fused GEMM + UNMASKED sum-of-exp per row (mask handled by ntx_pairs).
// Counted-vmcnt depth-2 pipeline over triple-buffered LDS (tile t+2's loads
// issue during tile t's compute; per-tile wait vmcnt(4) -- never a full drain
// in the loop). 512 blocks (2/CU), 4 waves x 64 rows each.
//
// XCD-AWARE SWIZZLE (the one change vs the 121.0 µs round-8 source): with
// bid->XCD round-robin (xcd = bid & 7), colblk = (bid&7) | ((bid>>3 & 1)<<3)
// pins each XCD to exactly 2 colblks -> its hot B working set is 2 x 256 KB
// = 512 KB, resident in the 4 MB per-XCD L2. Staging becomes an L2-hit
// stream instead of an L3-bandwidth-bound one (the invariant ~5-6 TB/s wall
// every previous schedule variant hit).
__global__ __launch_bounds__(256, 2)
void ntx_lse(const unsigned short* __restrict__ A, const unsigned short* __restrict__ Bm,
             float* __restrict__ rowsum) {
    __shared__ __align__(128) unsigned char Bs[3][CT * 512];  // 48 KB

    const int wave = threadIdx.x >> 6;
    const int lane = threadIdx.x & 63;
    const int g    = lane >> 4;    // 0..3 (k-quad)
    const int n16  = lane & 15;    // 0..15

    const int bid    = blockIdx.x;
    const int u      = bid >> 3;
    const int colblk = (bid & 7) | ((u & 1) << 3);  // 0..15, 2 per XCD
    const int rowblk = u >> 1;                      // 0..31
    const int row0 = rowblk * RT + wave * 64;       // this wave's 64 rows
    const int col0 = colblk * CPB;

    // A fragments for 64 rows x K=256 in registers (128 VGPRs).
    // A-operand layout: m = lane&15, k = (lane>>4)*8 + j
    bf16x8 afrag[4][8];
    #pragma unroll
    for (int rs = 0; rs < 4; ++rs) {
        const int r = row0 + rs * 16 + n16;
        #pragma unroll
        for (int k = 0; k < 8; ++k)
            afrag[rs][k] = __builtin_bit_cast(
                bf16x8, *(const u32x4*)(A + (size_t)r * D + k * 32 + g * 8));
    }

    float acc[4][4];
    #pragma unroll
    for (int rs = 0; rs < 4; ++rs)
        #pragma unroll
        for (int q = 0; q < 4; ++q) acc[rs][q] = 0.f;

    unsigned char* b0 = &Bs[0][0];
    unsigned char* b1 = &Bs[1][0];
    unsigned char* b2 = &Bs[2][0];

    // prologue: tiles 0 and 1 in flight (8 loads/wave)
    stage_tile4(Bm, col0,      wave, lane, b0);
    stage_tile4(Bm, col0 + CT, wave, lane, b1);

    for (int t = 0; t < NTILES - 1; ++t) {
        // counted wait: completes tile t's 4 loads; tile t+1's 4 stay in flight
        asm volatile("s_waitcnt vmcnt(4)" ::: "memory");
        __builtin_amdgcn_s_barrier();
        __builtin_amdgcn_sched_barrier(0);

        if (t + 2 < NTILES)
            tile_step<true >(Bm, col0 + (t + 2) * CT, wave, lane, b0, b2, afrag, acc);
        else
            tile_step<false>(Bm, 0, wave, lane, b0, b2, afrag, acc);

        unsigned char* tmp = b0; b0 = b1; b1 = b2; b2 = tmp;
    }
    // epilogue tile: only now drain fully
    asm volatile("s_waitcnt vmcnt(0)" ::: "memory");
    __builtin_amdgcn_s_barrier();
    __builtin_amdgcn_sched_barrier(0);
    tile_step<false>(Bm, 0, wave, lane, b0, b2, afrag, acc);

    // reduce partial row sums across the 16 lanes sharing each row group
    #pragma unroll
    for (int rs = 0; rs < 4; ++rs)
        #pragma unroll
        for (int q = 0; q < 4; ++q) {
            float v = acc[rs][q];
            v += __shfl_xor(v, 1);
            v += __shfl_xor(v, 2);
            v += __shfl_xor(v, 4);
            v += __shfl_xor(v, 8);
            if (n16 == 0)
                atomicAdd(&rowsum[row0 + rs * 16 + g * 4 + q], v);
        }
}

// loss = mean(log(rowsum) - diag). grid = N/256, one atomic per block.
__global__ void ntx_finish(const float* __restrict__ diag,
                           const float* __restrict__ rowsum,
                           float* __restrict__ out) {
    __shared__ float red[4];
    const int i = blockIdx.x * 256 + threadIdx.x;
    float s = logf(rowsum[i]) - diag[i];
    #pragma unroll
    for (int o = 32; o; o >>= 1) s += __shfl_xor(s, o);
    if ((threadIdx.x & 63) == 0) red[threadIdx.x >> 6] = s;
    __syncthreads();
    if (threadIdx.x == 0)
        atomicAdd(out, (red[0] + red[1] + red[2] + red[3]) * (1.0f / (float)N));
}

extern "C" void kernel_launch(void* const* d_in, const int* in_sizes, int n_in,
                              void* d_out, int out_size, void* d_ws, size_t ws_size,
                              hipStream_t stream) {
    const float* im     = (const float*)d_in[0];
    const float* rec    = (const float*)d_in[1];
    const int*   labels = (const int*)d_in[2];
    float* out = (float*)d_out;

    unsigned short* A  = (unsigned short*)d_ws;           // 4 MB bf16 im_n * INV_TAU*LOG2E
    unsigned short* Bm = A + (size_t)N * D;               // 4 MB bf16 rec_n
    float* diag   = (float*)(Bm + (size_t)N * D);         // 32 KB
    float* rowsum = diag + N;                             // 32 KB
    int*   cnt    = (int*)(rowsum + N);                   // 4 KB
    int*   bucket = cnt + 1024;                           // 384 KB

    ntx_prep<<<N / 4, 256, 0, stream>>>(im, rec, A, Bm, diag, rowsum, cnt, out);
    ntx_bucket<<<N / 256, 256, 0, stream>>>(labels, cnt, bucket);
    ntx_pairs<<<N / 4, 256, 0, stream>>>(A, Bm, labels, cnt, bucket, rowsum);
    ntx_lse<<<(N / RT) * CSPLIT, 256, 0, stream>>>(A, Bm, rowsum);
    ntx_finish<<<N / 256, 256, 0, stream>>>(diag, rowsum, out);
}